// Round 5
// baseline (119.568 us; speedup 1.0000x reference)
//
#include <hip/hip_runtime.h>

// Problem constants (match reference): B=8192, P=32, D=128, V=100000
#define BB 8192
#define PP 32
#define DD 128

// Two batch rows per 256-thread block (4 waves), 64 (b,p) pairs per block.
//
// Phase 1 (coalesced gather -> LDS): wave w owns row brow=w>>1, positions
// p in [16*(w&1), 16*(w&1)+16). Each iteration a 32-lane half loads one
// full 512B embed row (lane hl reads bytes hl*16..hl*16+15 -> 8 cache
// lines, MSHR-merged) and ds_write_b128s it into the LDS tile. This
// replaces round-4's fully-divergent gather (64 distinct lines per wave
// instruction -> TCP tag-lookup bound, ~28us).
//
// Phase 2 (lane-per-pair dot from LDS): wave w computes quarter w (chunks
// 8w..8w+7) of all 64 pair dots; lane l owns pair l. Chunk order is
// rotated, c = 8w + ((j+l)&7), so the 64 lanes spread uniformly over all
// 8 bank-groups -> hits the inherent 8-cyc/wave ds_read_b128 floor, no
// conflict penalty. No per-pair shuffles (round-2/3's VALU cost).
//
// Phase 3: softplus on 64 lanes + one wave reduction -> per-block partial.
__global__ __launch_bounds__(256) void hs_loss_kernel(
    const float* __restrict__ hidden,      // [B, D]
    const int*   __restrict__ path,        // [B, P]
    const int*   __restrict__ path_len,    // [B]
    const int*   __restrict__ code,        // [B, P]
    const float* __restrict__ embed,       // [V, D]
    float2* __restrict__ partials)         // [grid] {loss_sum, valid_count}
{
    const int tid  = threadIdx.x;
    const int lane = tid & 63;
    const int w    = tid >> 6;             // wave id, 0..3
    const int b0   = blockIdx.x * 2;

    __shared__ float elds[64 * DD];        // 64 embed rows (unpadded), 32 KB
    __shared__ float hlds[2 * DD];         // 2 hidden rows, 1 KB
    __shared__ float part[4][64];          // per-quarter dot partials, 1 KB

    // stage hidden: 2 rows * 128 floats = 256 floats, one per thread
    hlds[tid] = hidden[(size_t)b0 * DD + tid];

    const int lenA = path_len[b0];
    const int lenB = path_len[b0 + 1];

    // ---- phase 1: coalesced gather of valid embed rows into LDS ----
    {
        const int brow  = w >> 1;          // which batch row this wave loads
        const int pbase = (w & 1) * 16;    // p-range start
        const int lenw  = brow ? lenB : lenA;
        const int half  = lane >> 5;       // which of the 2 rows this instr
        const int hl    = lane & 31;       // lane within half
        #pragma unroll
        for (int j = 0; j < 8; ++j) {
            const int pj = pbase + 2 * j;
            if (pj < lenw) {               // wave-uniform branch
                // pair1 may be past len: clamp (writes duplicate row into
                // an unused slot; masked out in phase 3)
                const int p   = min(pj + half, lenw - 1);
                const int idx = path[(b0 + brow) * PP + p];
                const float4 e = ((const float4*)(embed + (size_t)idx * DD))[hl];
                const int slot = brow * 32 + pj + half;
                ((float4*)elds)[slot * 32 + hl] = e;
            }
        }
    }
    __syncthreads();

    // ---- phase 2: lane-per-pair quarter-dots from LDS, rotated chunks ----
    float acc = 0.0f;
    {
        const float4* hrow = (const float4*)(hlds + (lane >> 5) * DD);
        #pragma unroll
        for (int j = 0; j < 8; ++j) {
            const int c = 8 * w + ((j + lane) & 7);   // rotation kills conflicts
            const float4 e = ((const float4*)elds)[lane * 32 + c];
            const float4 h = hrow[c];
            acc += e.x * h.x + e.y * h.y + e.z * h.z + e.w * h.w;
        }
    }
    part[w][lane] = acc;
    __syncthreads();

    // ---- phase 3: combine quarters, softplus, block reduction ----
    if (tid < 64) {
        const float dot = part[0][tid] + part[1][tid]
                        + part[2][tid] + part[3][tid];
        const int p   = tid & 31;
        const int bl  = tid >> 5;
        const int len = bl ? lenB : lenA;
        float loss = 0.0f;
        if (p < len) {
            const int cd = code[(b0 + bl) * PP + p];
            // loss = softplus(code ? -dot : dot), stable BCE form
            const float z = cd ? -dot : dot;
            loss = fmaxf(z, 0.0f) + __logf(1.0f + __expf(-fabsf(z)));
        }
        #pragma unroll
        for (int m = 1; m <= 32; m <<= 1) loss += __shfl_xor(loss, m);
        if (tid == 0)
            partials[blockIdx.x] = make_float2(loss, (float)(lenA + lenB));
    }
}

// Single-block reduction of the 4096 per-block partials + final divide.
__global__ __launch_bounds__(1024) void hs_finalize_kernel(
    const float2* __restrict__ partials, float* __restrict__ out)
{
    const int tid = threadIdx.x;
    float ls = 0.0f, cs = 0.0f;
    #pragma unroll
    for (int k = 0; k < (BB / 2) / 1024; ++k) {
        const float2 v = partials[tid + k * 1024];
        ls += v.x;
        cs += v.y;
    }
    #pragma unroll
    for (int m = 1; m <= 32; m <<= 1) {
        ls += __shfl_xor(ls, m);
        cs += __shfl_xor(cs, m);
    }
    __shared__ float s_l[16], s_c[16];
    const int wave = tid >> 6;
    if ((tid & 63) == 0) { s_l[wave] = ls; s_c[wave] = cs; }
    __syncthreads();
    if (tid == 0) {
        float L = 0.0f, C = 0.0f;
        #pragma unroll
        for (int wv = 0; wv < 16; ++wv) { L += s_l[wv]; C += s_c[wv]; }
        out[0] = L / C;
    }
}

extern "C" void kernel_launch(void* const* d_in, const int* in_sizes, int n_in,
                              void* d_out, int out_size, void* d_ws, size_t ws_size,
                              hipStream_t stream) {
    const float* hidden   = (const float*)d_in[0];  // [B, D] f32
    // d_in[1] = target (unused by the reference computation)
    const int*   path     = (const int*)d_in[2];    // [B, P]
    const int*   path_len = (const int*)d_in[3];    // [B]
    const int*   code     = (const int*)d_in[4];    // [B, P]
    const float* embed    = (const float*)d_in[5];  // [V, D] f32
    float*  out      = (float*)d_out;
    float2* partials = (float2*)d_ws;               // 4096 * 8B = 32 KB

    hs_loss_kernel<<<BB / 2, 256, 0, stream>>>(hidden, path, path_len, code,
                                               embed, partials);
    hs_finalize_kernel<<<1, 1024, 0, stream>>>(partials, out);
}

// Round 6
// 101.458 us; speedup vs baseline: 1.1785x; 1.1785x over previous
//
#include <hip/hip_runtime.h>

// Problem constants (match reference): B=8192, P=32, D=128, V=100000
#define BB 8192
#define PP 32
#define DD 128

// Barrier-free wave-private scheme. One wave (64 lanes) owns 2 batch rows
// = 64 (b,p) pair slots; block = 4 waves = 8 rows; grid = 1024 blocks.
//
// Phase 1 (coalesced gather + partial dots): quarter q (16 lanes) handles
// pair (row=q>>1, p=(q&1)*16+j) for j=0..15. Per pair the 16 lanes load the
// full 512B embed row as 2 float4s each (256B-contiguous per quarter ->
// 8 cache-line lookups/pair; R4's divergent walk needed 32). Lane keeps an
// 8-element partial (8 FMAs = minimal MAC cost) and writes ONE b32 to a
// wave-private LDS slice (stride 17 -> only 2-way bank aliasing = free).
// All 32 valid gathers per wave are independent -> deep MLP.
//
// Phase 2: lane l sums the 16 partials of pair l (17-stride read = bank
// bijection, 2-way free). Same-wave LDS -> NO __syncthreads anywhere; the
// compiler's lgkmcnt waits are sufficient. (R5's cross-wave barriers + 34KB
// LDS collapsed occupancy to 33%; this slice is 4.25KB/wave, 17KB/block.)
//
// Phase 3: softplus on all 64 lanes, ballot for the valid count, 6-step
// shfl reduce, one float2 partial per wave (no atomics).
__global__ __launch_bounds__(256) void hs_loss_kernel(
    const float* __restrict__ hidden,      // [B, D]
    const int*   __restrict__ path,        // [B, P]
    const int*   __restrict__ path_len,    // [B]
    const int*   __restrict__ code,        // [B, P]
    const float* __restrict__ embed,       // [V, D]
    float2* __restrict__ partials)         // [4096] {loss_sum, valid_count}
{
    const int tid = threadIdx.x;
    const int w   = tid >> 6;              // wave in block, 0..3
    const int l   = tid & 63;              // lane
    const int ql  = l & 15;                // lane within quarter
    const int b0  = blockIdx.x * 8 + w * 2;  // wave's first batch row
    const int b   = b0 + (l >> 5);         // this lane's row (phases 1&3)

    __shared__ float plds[4][64 * 17];     // per-wave 4.25KB slices, 17KB tot
    float* const myp = plds[w];

    // ---- preload (all coalesced) ----
    // pairs of rows (b0, b0+1) are contiguous: lane l caches pair l's
    // path index and code directly.
    const int   idx_all = path[b0 * PP + l];
    const int   cd_all  = code[b0 * PP + l];
    const int   len     = path_len[b];     // uniform per 32-lane half
    const float4 h0 = ((const float4*)hidden)[b * (DD / 4) + ql];
    const float4 h1 = ((const float4*)hidden)[b * (DD / 4) + 16 + ql];

    const int pbase = (l & 16);            // quarter's p-range: 0 or 16

    // ---- phase 1 ----
    #pragma unroll
    for (int j = 0; j < 16; ++j) {
        const int p   = pbase + j;         // uniform per quarter
        const int pid = (l & 48) + j;      // flat pair id == source lane
        const int idx = __shfl(idx_all, pid);
        float partial = 0.0f;
        if (p < len) {                     // quarter-uniform exec mask
            const float4* erow = (const float4*)(embed + (size_t)idx * DD);
            const float4 e0 = erow[ql];
            const float4 e1 = erow[16 + ql];
            partial = e0.x * h0.x + e0.y * h0.y + e0.z * h0.z + e0.w * h0.w
                    + e1.x * h1.x + e1.y * h1.y + e1.z * h1.z + e1.w * h1.w;
        }
        myp[pid * 17 + ql] = partial;      // invalid pairs write 0
    }

    // ---- phase 2: same-wave LDS, no barrier ----
    float dot = 0.0f;
    #pragma unroll
    for (int k = 0; k < 16; ++k) dot += myp[l * 17 + k];

    // ---- phase 3 ----
    const bool valid = (l & 31) < len;
    float loss = 0.0f;
    if (valid) {
        // loss = softplus(code ? -dot : dot), stable BCE form
        const float z = cd_all ? -dot : dot;
        loss = fmaxf(z, 0.0f) + __logf(1.0f + __expf(-fabsf(z)));
    }
    const unsigned long long bal = __ballot(valid);
    #pragma unroll
    for (int m = 1; m <= 32; m <<= 1) loss += __shfl_xor(loss, m);
    if (l == 0)
        partials[blockIdx.x * 4 + w] =
            make_float2(loss, (float)__popcll(bal));
}

// Single-block reduction of the 4096 per-wave partials + final divide.
__global__ __launch_bounds__(1024) void hs_finalize_kernel(
    const float2* __restrict__ partials, float* __restrict__ out)
{
    const int tid = threadIdx.x;
    float ls = 0.0f, cs = 0.0f;
    #pragma unroll
    for (int k = 0; k < 4; ++k) {         // 4096 partials / 1024 threads
        const float2 v = partials[tid + k * 1024];
        ls += v.x;
        cs += v.y;
    }
    #pragma unroll
    for (int m = 1; m <= 32; m <<= 1) {
        ls += __shfl_xor(ls, m);
        cs += __shfl_xor(cs, m);
    }
    __shared__ float s_l[16], s_c[16];
    const int wave = tid >> 6;
    if ((tid & 63) == 0) { s_l[wave] = ls; s_c[wave] = cs; }
    __syncthreads();
    if (tid == 0) {
        float L = 0.0f, C = 0.0f;
        #pragma unroll
        for (int wv = 0; wv < 16; ++wv) { L += s_l[wv]; C += s_c[wv]; }
        out[0] = L / C;
    }
}

extern "C" void kernel_launch(void* const* d_in, const int* in_sizes, int n_in,
                              void* d_out, int out_size, void* d_ws, size_t ws_size,
                              hipStream_t stream) {
    const float* hidden   = (const float*)d_in[0];  // [B, D] f32
    // d_in[1] = target (unused by the reference computation)
    const int*   path     = (const int*)d_in[2];    // [B, P]
    const int*   path_len = (const int*)d_in[3];    // [B]
    const int*   code     = (const int*)d_in[4];    // [B, P]
    const float* embed    = (const float*)d_in[5];  // [V, D] f32
    float*  out      = (float*)d_out;
    float2* partials = (float2*)d_ws;               // 4096 * 8B = 32 KB

    hs_loss_kernel<<<BB / 8, 256, 0, stream>>>(hidden, path, path_len, code,
                                               embed, partials);
    hs_finalize_kernel<<<1, 1024, 0, stream>>>(partials, out);
}

// Round 7
// 100.489 us; speedup vs baseline: 1.1899x; 1.0096x over previous
//
#include <hip/hip_runtime.h>

// Problem constants (match reference): B=8192, P=32, D=128, V=100000
#define BB 8192
#define PP 32
#define DD 128

// One wave per batch row; block = 4 waves = 4 rows; grid = BB/4 = 2048.
//
// Phase 1a: quarter q (16 lanes) owns pairs pid = 8q..8q+7. ALL 16 gathers
// (8 pairs x 2 float4; 16 lanes x 32B = the full 512B embed row, coalesced)
// are issued into a register array BEFORE any consumption — R6's loop ended
// each iteration with a ds_write consuming that iteration's loads, so the
// compiler's vmcnt waits serialized it to ~2-4 loads in flight; this
// two-loop structure keeps 16 in flight per wave (x16 waves/CU).
//
// Phase 1b: 8-element partial dot per lane + ONE ds_write_b32 into a
// wave-private stride-17 LDS slice (2-way bank aliasing only = free).
//
// Phase 2: wave-half-split sum of each pair's 16 partials (8 ds_read_b32
// per lane, stride-17 = bank bijection; + one shfl_xor(32) combine).
//
// Phase 3: softplus on lanes 0..31, 6-step shfl reduce, one float2 partial
// per wave. No __syncthreads anywhere (same-wave LDS only).
__global__ __launch_bounds__(256) void hs_loss_kernel(
    const float* __restrict__ hidden,      // [B, D]
    const int*   __restrict__ path,        // [B, P]
    const int*   __restrict__ path_len,    // [B]
    const int*   __restrict__ code,        // [B, P]
    const float* __restrict__ embed,       // [V, D]
    float2* __restrict__ partials)         // [BB] {loss_sum, len} per row
{
    const int tid = threadIdx.x;
    const int w   = tid >> 6;              // wave in block, 0..3
    const int l   = tid & 63;              // lane
    const int q   = l >> 4;                // quarter, 0..3
    const int ql  = l & 15;                // lane within quarter
    const int lp  = l & 31;                // pair id for phases 2/3
    const int b   = blockIdx.x * 4 + w;    // this wave's batch row

    __shared__ float plds[4][PP * 17];     // 4 wave-private slices, 8.5 KB
    float* const myp = plds[w];

    const int len   = path_len[b];         // wave-uniform
    const int idx_l = path[b * PP + lp];   // lane lp holds pair lp's index
    const int cd_l  = code[b * PP + lp];   // (lanes 32-63 duplicate 0-31)

    const float4 h0 = ((const float4*)hidden)[b * (DD / 4) + ql];
    const float4 h1 = ((const float4*)hidden)[b * (DD / 4) + 16 + ql];

    // ---- phase 1a: issue all 16 independent gathers up-front ----
    float4 e0[8], e1[8];
    #pragma unroll
    for (int j = 0; j < 8; ++j) {
        const int pid = q * 8 + j;         // uniform within quarter
        const int idx = __shfl(idx_l, pid);
        if (pid < len) {                   // quarter-uniform exec mask
            const float4* erow = (const float4*)(embed + (size_t)idx * DD);
            e0[j] = erow[ql];
            e1[j] = erow[16 + ql];
        }
    }

    // ---- phase 1b: partial dots + single b32 write per pair-lane ----
    #pragma unroll
    for (int j = 0; j < 8; ++j) {
        const int pid = q * 8 + j;
        if (pid < len) {
            const float p8 =
                e0[j].x * h0.x + e0[j].y * h0.y + e0[j].z * h0.z + e0[j].w * h0.w +
                e1[j].x * h1.x + e1[j].y * h1.y + e1[j].z * h1.z + e1[j].w * h1.w;
            myp[pid * 17 + ql] = p8;
        }
    }

    // ---- phase 2: half-split partial-sum (same-wave LDS, no barrier) ----
    const int kbase = (l >> 5) * 8;        // lanes 0-31: k=0..7; 32-63: 8..15
    float psum = 0.0f;
    #pragma unroll
    for (int k = 0; k < 8; ++k) psum += myp[lp * 17 + kbase + k];
    const float dot = psum + __shfl_xor(psum, 32);   // full 16-partial sum

    // ---- phase 3: softplus + wave reduction ----
    float loss = 0.0f;
    if (l < 32 && lp < len) {
        // loss = softplus(code ? -dot : dot), stable BCE form
        const float z = cd_l ? -dot : dot;
        loss = fmaxf(z, 0.0f) + __logf(1.0f + __expf(-fabsf(z)));
    }
    #pragma unroll
    for (int m = 1; m <= 32; m <<= 1) loss += __shfl_xor(loss, m);
    if (l == 0) partials[b] = make_float2(loss, (float)len);
}

// Single-block reduction of the 8192 per-wave partials + final divide.
__global__ __launch_bounds__(1024) void hs_finalize_kernel(
    const float2* __restrict__ partials, float* __restrict__ out)
{
    const int tid = threadIdx.x;
    float ls = 0.0f, cs = 0.0f;
    #pragma unroll
    for (int k = 0; k < BB / 1024; ++k) {
        const float2 v = partials[tid + k * 1024];
        ls += v.x;
        cs += v.y;
    }
    #pragma unroll
    for (int m = 1; m <= 32; m <<= 1) {
        ls += __shfl_xor(ls, m);
        cs += __shfl_xor(cs, m);
    }
    __shared__ float s_l[16], s_c[16];
    const int wave = tid >> 6;
    if ((tid & 63) == 0) { s_l[wave] = ls; s_c[wave] = cs; }
    __syncthreads();
    if (tid == 0) {
        float L = 0.0f, C = 0.0f;
        #pragma unroll
        for (int wv = 0; wv < 16; ++wv) { L += s_l[wv]; C += s_c[wv]; }
        out[0] = L / C;
    }
}

extern "C" void kernel_launch(void* const* d_in, const int* in_sizes, int n_in,
                              void* d_out, int out_size, void* d_ws, size_t ws_size,
                              hipStream_t stream) {
    const float* hidden   = (const float*)d_in[0];  // [B, D] f32
    // d_in[1] = target (unused by the reference computation)
    const int*   path     = (const int*)d_in[2];    // [B, P]
    const int*   path_len = (const int*)d_in[3];    // [B]
    const int*   code     = (const int*)d_in[4];    // [B, P]
    const float* embed    = (const float*)d_in[5];  // [V, D] f32
    float*  out      = (float*)d_out;
    float2* partials = (float2*)d_ws;               // 8192 * 8B = 64 KB

    hs_loss_kernel<<<BB / 4, 256, 0, stream>>>(hidden, path, path_len, code,
                                               embed, partials);
    hs_finalize_kernel<<<1, 1024, 0, stream>>>(partials, out);
}